// Round 9
// baseline (331.645 us; speedup 1.0000x reference)
//
#include <hip/hip_runtime.h>

#define N_NODES 50000
#define N_EDGES 800000
#define R_REL   8

// per-dst-tile binning (16 nodes per tile)
#define TNBKT   3125                     // 50000/16 bins
#define TCAP    512                      // records per bin (mean 256, +16 sigma)
#define SLAB    2048                     // edges per bin-block
#define BINBLK  ((N_EDGES + SLAB - 1) / SLAB)  // 391

// phased fused kernel geometry (normal launches, NO cooperative API)
#define NBLK    625                      // blocks; co-resident by capacity
#define TPB     5                        // tiles per block: 625*5 = 3125 exact
#define SEGST   648                      // slab seg stride (shorts) = 81 x 16B (odd)
                                         // row stride 40 shorts -> bank-uniform

typedef float  f32x4  __attribute__((ext_vector_type(4)));
typedef __bf16 bf16x8 __attribute__((ext_vector_type(8)));

__device__ __forceinline__ unsigned short f2bf(float f) {
    unsigned int u = __float_as_uint(f);
    u = (u + 0x7FFFu + ((u >> 16) & 1u)) >> 16;   // RNE
    return (unsigned short)u;
}
__device__ __forceinline__ float bflo(unsigned int u) { return __uint_as_float(u << 16); }
__device__ __forceinline__ float bfhi(unsigned int u) { return __uint_as_float(u & 0xFFFF0000u); }

__device__ __forceinline__ void acc8(float* a, uint4 u) {
    a[0] += bflo(u.x); a[1] += bfhi(u.x);
    a[2] += bflo(u.y); a[3] += bfhi(u.y);
    a[4] += bflo(u.z); a[5] += bfhi(u.z);
    a[6] += bflo(u.w); a[7] += bfhi(u.w);
}

// ---------------- merged prep: histogram dst-tile binning + converts (R5 proven) ----------------

#define W1_ELEMS (9 * 128 * 128)   // NBt=8
#define W2_ELEMS (9 * 64 * 128)    // NBt=4
#define N4       (N_NODES * 32)    // 1.6M float4 groups
#define NB_CVT   ((N4 + 255) / 256)            // 6250
#define NB_PREP  (BINBLK + NB_CVT)             // 6641

__global__ __launch_bounds__(256) void k_prep(
    const int* __restrict__ src, const int* __restrict__ dst,
    const int* __restrict__ et, int* __restrict__ gcur,
    unsigned* __restrict__ gbin,
    const float* __restrict__ x, unsigned short* __restrict__ xb,
    const float* __restrict__ root1, const float* __restrict__ W1,
    const float* __restrict__ root2, const float* __restrict__ W2,
    unsigned short* __restrict__ Wt1, unsigned short* __restrict__ Wt2)
{
    __shared__ int hist[TNBKT];
    __shared__ int base[TNBKT];
    const int t = threadIdx.x;

    if (blockIdx.x < BINBLK) {
        // ---------- bin branch: LDS histogram -> contiguous-run writes ----------
        const int e0 = blockIdx.x * SLAB;
        for (int i = t; i < TNBKT; i += 256) hist[i] = 0;
        __syncthreads();
#pragma unroll
        for (int i = 0; i < SLAB / 256; ++i) {
            int e = e0 + i * 256 + t;
            if (e < N_EDGES) atomicAdd(&hist[dst[e] >> 4], 1);
        }
        __syncthreads();
        for (int i = t; i < TNBKT; i += 256) {
            int h = hist[i];
            base[i] = (h > 0) ? atomicAdd(&gcur[i], h) : 0;
            hist[i] = 0;   // reuse as sub-cursor
        }
        __syncthreads();
#pragma unroll
        for (int i = 0; i < SLAB / 256; ++i) {
            int e = e0 + i * 256 + t;
            if (e < N_EDGES) {
                int d = dst[e];
                int b = d >> 4;
                int sub = atomicAdd(&hist[b], 1);
                int pos = base[b] + sub;
                unsigned rec = ((unsigned)src[e] << 7) | (unsigned)((d & 15) * 8 + et[e]);
                if (pos < TCAP) gbin[(size_t)b * TCAP + pos] = rec;
            }
        }
        return;
    }

    // ---------- convert branch ----------
    const int idx = (blockIdx.x - BINBLK) * 256 + t;
    if (idx < N4) {
        float4 v = *(const float4*)(x + (size_t)idx * 4);
        ushort4 o;
        o.x = f2bf(v.x); o.y = f2bf(v.y); o.z = f2bf(v.z); o.w = f2bf(v.w);
        *(ushort4*)(xb + (size_t)idx * 4) = o;
    }
    if (idx < W1_ELEMS) {
        int j    = idx & 7;
        int lane = (idx >> 3) & 63;
        int r    = idx >> 9;
        int nb   = r & 7;        // NBt = 8
        int r2   = r >> 3;
        int kk   = r2 & 3;
        int seg  = r2 >> 2;
        int k = kk * 32 + (lane >> 4) * 8 + j;
        int n = nb * 16 + (lane & 15);
        float v = (seg == 0) ? root1[k * 128 + n] : W1[((seg - 1) * 128 + k) * 128 + n];
        Wt1[idx] = f2bf(v);
    } else if (idx < W1_ELEMS + W2_ELEMS) {
        int i2   = idx - W1_ELEMS;
        int j    = i2 & 7;
        int lane = (i2 >> 3) & 63;
        int r    = i2 >> 9;
        int nb   = r & 3;        // NBt = 4
        int r2   = r >> 2;
        int kk   = r2 & 3;
        int seg  = r2 >> 2;
        int k = kk * 32 + (lane >> 4) * 8 + j;
        int n = nb * 16 + (lane & 15);
        float v = (seg == 0) ? root2[k * 64 + n] : W2[((seg - 1) * 128 + k) * 64 + n];
        Wt2[i2] = f2bf(v);
    }
}

// ---------------- phased fused layer (normal launch, 625 blocks x 5 tiles) ----------------
// Phase q (0..3): gather ONLY byte-quarter q of each neighbor row. One 64B line
// per edge per phase; distinct-line set of a quarter = 50000*64B = 3.2MB < 4MiB
// per-XCD L2, so after first touch the gather hits L2 (~250cy) instead of L3
// (~600cy). MSHR model (R4/R6 data): per-CU in-flight line cap ~40; rate =
// cap/latency, so latency/2.4 => gather-rate x2.4. All 625 blocks fit
// co-resident (LDS 32KB -> 5/CU, waves -> 4/CU; need 2.44/CU) and a normal
// launch starts them together; phase alignment is approximate (no grid sync
// needed -- correctness never depends on it).
// The quarter's MFMA K-slice (Bp[(seg*4+q)...]) runs immediately after each
// tile's gather; accumulators acc[TPB] persist in registers across phases
// (static indices only). Slab: seg stride 648 shorts (odd multiple of 16B),
// row stride 40 shorts -> writes (16 chains x 4 subs), reads (16 tc x 4 quad)
// and root stage all land 8 lanes per 16B bank-slot = 2/bank = conflict-free.

template <int FOUT, bool RELU, bool OUT_BF16>
__global__ __launch_bounds__(512) void k_phase(
    const unsigned short* __restrict__ xin,   // [N,128] bf16 (gather + root src)
    const unsigned short* __restrict__ WtP,   // fragment-ordered weights
    const float* __restrict__ bias,
    const int* __restrict__ gcnt,             // [TNBKT]
    const unsigned* __restrict__ gbin,        // [TNBKT][TCAP]
    unsigned short* __restrict__ outb,        // [N,FOUT] bf16 (if OUT_BF16)
    float* __restrict__ outf)                 // [N,FOUT] fp32 (else)
{
    constexpr int NBt = FOUT / 16;
    __shared__ unsigned short sorted[TPB][TCAP];                 // 5 KB
    __shared__ unsigned short degb[TPB][128];                    // 1.25 KB
    __shared__ unsigned short begb[TPB][128];                    // 1.25 KB
    __shared__ __align__(16) unsigned short slab[2 * SEGST * 9]; // 23.3 KB
    __shared__ int dcnt[128];
    __shared__ int kcur[128];

    const int t = threadIdx.x;
    const int tile0 = blockIdx.x * TPB;

    // ---- CSR meta build (per tile: histogram -> wave-0 scan -> scatter) ----
    for (int ti = 0; ti < TPB; ++ti) {
        if (t < 128) { dcnt[t] = 0; kcur[t] = 0; }
        __syncthreads();
        const int tile = tile0 + ti;
        const int nraw = gcnt[tile];
        const int n = nraw < TCAP ? nraw : TCAP;
        unsigned rec = 0;
        if (t < n) {
            rec = gbin[(size_t)tile * TCAP + t];
            atomicAdd(&dcnt[rec & 127], 1);
        }
        __syncthreads();
        if (t < 64) {
            int d0 = dcnt[2 * t], d1 = dcnt[2 * t + 1];
            int s = d0 + d1, inc = s;
#pragma unroll
            for (int off = 1; off < 64; off <<= 1) {
                int y = __shfl_up(inc, off, 64);
                if (t >= off) inc += y;
            }
            int excl = inc - s;
            begb[ti][2 * t]     = (unsigned short)excl;
            begb[ti][2 * t + 1] = (unsigned short)(excl + d0);
            degb[ti][2 * t]     = (unsigned short)d0;
            degb[ti][2 * t + 1] = (unsigned short)d1;
        }
        __syncthreads();
        if (t < n) {
            int key = rec & 127;
            int pos = atomicAdd(&kcur[key], 1);
            sorted[ti][(int)begb[ti][key] + pos] = (unsigned short)(rec >> 7);
        }
        __syncthreads();
    }

    // ---- phased gather + MFMA ----
    const int lane = t & 63;
    const int w    = t >> 6;
    const int quad = lane >> 4;
    const int tc   = lane & 15;
    const int sub  = t & 3;          // 16B feature slice within the quarter
    const int key  = t >> 2;         // chain id: nl*8 + rel
    const int rel  = key & 7;
    const int nl   = key >> 3;

    f32x4 acc[TPB];
#pragma unroll
    for (int i = 0; i < TPB; ++i) acc[i] = (f32x4){0.f, 0.f, 0.f, 0.f};

    int buf = 0;
    for (int q = 0; q < 4; ++q) {
#pragma unroll
        for (int ti = 0; ti < TPB; ++ti) {
            unsigned short* sl = slab + buf * (SEGST * 9);
            const int node0 = (tile0 + ti) * 16;

            // root stage (seg 0), quarter q: 16 rows x 64B by threads 0-63
            if (t < 64) {
                int row = t >> 2, piece = t & 3;
                uint4 v = *(const uint4*)(xin + (size_t)(node0 + row) * 128 + q * 32 + piece * 8);
                *(uint4*)(sl + row * 40 + piece * 8) = v;
            }

            // gather quarter q: 4 lanes/chain, 16B/lane/edge, 4-edge ILP
            {
                const int deg = degb[ti][key];
                const int beg = begb[ti][key];
                const int end = beg + deg;
                const unsigned short* bx = xin + q * 32 + sub * 8;
                const unsigned short* srt = sorted[ti];
                float a[8];
#pragma unroll
                for (int i = 0; i < 8; ++i) a[i] = 0.f;
                int j = beg;
                for (; j + 3 < end; j += 4) {
                    int s0 = srt[j], s1 = srt[j + 1], s2 = srt[j + 2], s3 = srt[j + 3];
                    uint4 v0 = *(const uint4*)(bx + (size_t)s0 * 128);
                    uint4 v1 = *(const uint4*)(bx + (size_t)s1 * 128);
                    uint4 v2 = *(const uint4*)(bx + (size_t)s2 * 128);
                    uint4 v3 = *(const uint4*)(bx + (size_t)s3 * 128);
                    acc8(a, v0); acc8(a, v1); acc8(a, v2); acc8(a, v3);
                }
                if (j + 1 < end) {
                    int s0 = srt[j], s1 = srt[j + 1];
                    uint4 v0 = *(const uint4*)(bx + (size_t)s0 * 128);
                    uint4 v1 = *(const uint4*)(bx + (size_t)s1 * 128);
                    acc8(a, v0); acc8(a, v1);
                    j += 2;
                }
                if (j < end) {
                    uint4 v0 = *(const uint4*)(bx + (size_t)srt[j] * 128);
                    acc8(a, v0);
                }
                float scl = 1.f / (float)(deg > 1 ? deg : 1);
                unsigned pk0 = (unsigned)f2bf(a[0] * scl) | ((unsigned)f2bf(a[1] * scl) << 16);
                unsigned pk1 = (unsigned)f2bf(a[2] * scl) | ((unsigned)f2bf(a[3] * scl) << 16);
                unsigned pk2 = (unsigned)f2bf(a[4] * scl) | ((unsigned)f2bf(a[5] * scl) << 16);
                unsigned pk3 = (unsigned)f2bf(a[6] * scl) | ((unsigned)f2bf(a[7] * scl) << 16);
                *(uint4*)(sl + (1 + rel) * SEGST + nl * 40 + sub * 8) =
                    make_uint4(pk0, pk1, pk2, pk3);
            }

            __syncthreads();   // slab[buf] writes done; prev step's reads done

            if (w < NBt) {
                const bf16x8* Bp = (const bf16x8*)WtP;
                f32x4 av = acc[ti];
#pragma unroll
                for (int seg = 0; seg < 9; ++seg) {
                    bf16x8 af = *(const bf16x8*)(sl + seg * SEGST + tc * 40 + quad * 8);
                    bf16x8 bf = Bp[((seg * 4 + q) * NBt + w) * 64 + lane];
                    av = __builtin_amdgcn_mfma_f32_16x16x32_bf16(af, bf, av, 0, 0, 0);
                }
                acc[ti] = av;
            }
            buf ^= 1;   // odd step count per phase -> continuous alternation
        }
    }

    // ---- epilogue: D layout col = lane&15, row = quad*4 + reg ----
    if (w < NBt) {
        const int col = w * 16 + tc;
        const float bs = bias[col];
#pragma unroll
        for (int ti = 0; ti < TPB; ++ti) {
            const int node0 = (tile0 + ti) * 16;
#pragma unroll
            for (int i = 0; i < 4; ++i) {
                int r = node0 + quad * 4 + i;
                float v = acc[ti][i] + bs;
                if (RELU) v = fmaxf(v, 0.f);
                if (OUT_BF16) outb[(size_t)r * FOUT + col] = f2bf(v);
                else          outf[(size_t)r * FOUT + col] = v;
            }
        }
    }
}

// ---------------- launch ----------------

extern "C" void kernel_launch(void* const* d_in, const int* in_sizes, int n_in,
                              void* d_out, int out_size, void* d_ws, size_t ws_size,
                              hipStream_t stream) {
    const float* x     = (const float*)d_in[0];
    const int*   ei    = (const int*)d_in[1];  // [2][E]: row0=src, row1=dst
    const int*   et    = (const int*)d_in[2];  // [E]
    const float* W1    = (const float*)d_in[3];
    const float* root1 = (const float*)d_in[4];
    const float* b1    = (const float*)d_in[5];
    const float* W2    = (const float*)d_in[6];
    const float* root2 = (const float*)d_in[7];
    const float* b2    = (const float*)d_in[8];
    float* out = (float*)d_out;

    int* ws = (int*)d_ws;
    int* gcur = ws;                                   // [3200]
    unsigned* gbin = (unsigned*)(gcur + 3200);        // TNBKT*TCAP u32 = 6.4 MB
    unsigned short* xb  = (unsigned short*)(gbin + (size_t)TNBKT * TCAP); // 12.8 MB
    unsigned short* hb  = xb + (size_t)N_NODES * 128;                     // 12.8 MB
    unsigned short* Wt1 = hb + (size_t)N_NODES * 128;                     // 288 KB
    unsigned short* Wt2 = Wt1 + W1_ELEMS;                                 // 144 KB

    const int* esrc = ei;
    const int* edst = ei + N_EDGES;

    // memset + 3 normal dispatches: prep -> phased layer1 -> phased layer2
    hipMemsetAsync(gcur, 0, 3200 * sizeof(int), stream);
    k_prep<<<NB_PREP, 256, 0, stream>>>(esrc, edst, et, gcur, gbin,
                                        x, xb, root1, W1, root2, W2, Wt1, Wt2);

    k_phase<128, true,  true ><<<NBLK, 512, 0, stream>>>(xb, Wt1, b1, gcur, gbin, hb, nullptr);
    k_phase<64,  false, false><<<NBLK, 512, 0, stream>>>(hb, Wt2, b2, gcur, gbin, nullptr, out);
}

// Round 10
// 250.692 us; speedup vs baseline: 1.3229x; 1.3229x over previous
//
#include <hip/hip_runtime.h>

#define N_NODES 50000
#define N_EDGES 800000
#define R_REL   8

// per-dst-tile binning (16 nodes per tile == fused block tile)
#define TNBKT   3125                     // 50000/16 bins
#define TCAP    512                      // records per bin (mean 256, +16 sigma)
#define SLAB    4096                     // edges per bin-block (196 blocks = 0.77/CU,
                                         // ONE scheduling round; 2048 gave 391 = 1.53/CU
                                         // -> half the CUs ran two serial bin blocks)
#define BINBLK  ((N_EDGES + SLAB - 1) / SLAB)  // 196

typedef float  f32x4  __attribute__((ext_vector_type(4)));
typedef __bf16 bf16x8 __attribute__((ext_vector_type(8)));

__device__ __forceinline__ unsigned short f2bf(float f) {
    unsigned int u = __float_as_uint(f);
    u = (u + 0x7FFFu + ((u >> 16) & 1u)) >> 16;   // RNE
    return (unsigned short)u;
}
__device__ __forceinline__ float bflo(unsigned int u) { return __uint_as_float(u << 16); }
__device__ __forceinline__ float bfhi(unsigned int u) { return __uint_as_float(u & 0xFFFF0000u); }

__device__ __forceinline__ void acc16(float* a, uint4 u0, uint4 u1) {
    a[0]  += bflo(u0.x);   a[1]  += bfhi(u0.x);
    a[2]  += bflo(u0.y);   a[3]  += bfhi(u0.y);
    a[4]  += bflo(u0.z);   a[5]  += bfhi(u0.z);
    a[6]  += bflo(u0.w);   a[7]  += bfhi(u0.w);
    a[8]  += bflo(u1.x);   a[9]  += bfhi(u1.x);
    a[10] += bflo(u1.y);   a[11] += bfhi(u1.y);
    a[12] += bflo(u1.z);   a[13] += bfhi(u1.z);
    a[14] += bflo(u1.w);   a[15] += bfhi(u1.w);
}

// ---------------- merged prep: dst-tile binning + converts in ONE dispatch ----------------
// Blocks [0, BINBLK) bin edges to dst-tiles (record = src<<7 | localkey, 4B);
// blocks [BINBLK, ...) do x->bf16 convert + fragment-ordered weight packing.
// Bin blocks overlap the BW-bound convert stream.

#define W1_ELEMS (9 * 128 * 128)   // NBt=8
#define W2_ELEMS (9 * 64 * 128)    // NBt=4
#define N4       (N_NODES * 32)    // 1.6M float4 groups
#define NB_CVT   ((N4 + 255) / 256)            // 6250
#define NB_PREP  (BINBLK + NB_CVT)             // 6446

__global__ __launch_bounds__(256) void k_prep(
    const int* __restrict__ src, const int* __restrict__ dst,
    const int* __restrict__ et, int* __restrict__ gcur,
    unsigned* __restrict__ gbin,
    const float* __restrict__ x, unsigned short* __restrict__ xb,
    const float* __restrict__ root1, const float* __restrict__ W1,
    const float* __restrict__ root2, const float* __restrict__ W2,
    unsigned short* __restrict__ Wt1, unsigned short* __restrict__ Wt2)
{
    __shared__ int hist[TNBKT];
    __shared__ int base[TNBKT];
    const int t = threadIdx.x;

    if (blockIdx.x < BINBLK) {
        // ---------- bin branch: LDS histogram -> contiguous-run writes ----------
        const int e0 = blockIdx.x * SLAB;
        for (int i = t; i < TNBKT; i += 256) hist[i] = 0;
        __syncthreads();
#pragma unroll
        for (int i = 0; i < SLAB / 256; ++i) {
            int e = e0 + i * 256 + t;
            if (e < N_EDGES) atomicAdd(&hist[dst[e] >> 4], 1);
        }
        __syncthreads();
        for (int i = t; i < TNBKT; i += 256) {
            int h = hist[i];
            base[i] = (h > 0) ? atomicAdd(&gcur[i], h) : 0;
            hist[i] = 0;   // reuse as sub-cursor
        }
        __syncthreads();
#pragma unroll
        for (int i = 0; i < SLAB / 256; ++i) {
            int e = e0 + i * 256 + t;
            if (e < N_EDGES) {
                int d = dst[e];
                int b = d >> 4;
                int sub = atomicAdd(&hist[b], 1);
                int pos = base[b] + sub;
                unsigned rec = ((unsigned)src[e] << 7) | (unsigned)((d & 15) * 8 + et[e]);
                if (pos < TCAP) gbin[(size_t)b * TCAP + pos] = rec;
            }
        }
        return;
    }

    // ---------- convert branch ----------
    const int idx = (blockIdx.x - BINBLK) * 256 + t;
    if (idx < N4) {
        float4 v = *(const float4*)(x + (size_t)idx * 4);
        ushort4 o;
        o.x = f2bf(v.x); o.y = f2bf(v.y); o.z = f2bf(v.z); o.w = f2bf(v.w);
        *(ushort4*)(xb + (size_t)idx * 4) = o;
    }
    if (idx < W1_ELEMS) {
        int j    = idx & 7;
        int lane = (idx >> 3) & 63;
        int r    = idx >> 9;
        int nb   = r & 7;        // NBt = 8
        int r2   = r >> 3;
        int kk   = r2 & 3;
        int seg  = r2 >> 2;
        int k = kk * 32 + (lane >> 4) * 8 + j;
        int n = nb * 16 + (lane & 15);
        float v = (seg == 0) ? root1[k * 128 + n] : W1[((seg - 1) * 128 + k) * 128 + n];
        Wt1[idx] = f2bf(v);
    } else if (idx < W1_ELEMS + W2_ELEMS) {
        int i2   = idx - W1_ELEMS;
        int j    = i2 & 7;
        int lane = (i2 >> 3) & 63;
        int r    = i2 >> 9;
        int nb   = r & 3;        // NBt = 4
        int r2   = r >> 2;
        int kk   = r2 & 3;
        int seg  = r2 >> 2;
        int k = kk * 32 + (lane >> 4) * 8 + j;
        int n = nb * 16 + (lane & 15);
        float v = (seg == 0) ? root2[k * 64 + n] : W2[((seg - 1) * 128 + k) * 64 + n];
        Wt2[i2] = f2bf(v);
    }
}

// ---------------- fused: in-LDS CSR build + gather + MFMA (R4/R5 proven, 78 us) ----------------
// Gather-loop verdict after 9 rounds: the chain gather sits at the per-CU
// outstanding-line latency-product wall. Evidence: (R1) halving per-chain
// lines-in-flight -29%; (R5) compiler silently undoes source prefetch ->
// neutral; (R6) sched_barrier-forced pipeline -8%; (R9) phased quarter-gather
// (4 lines/chain instead of 8, +20 barrier steps) -50% despite L2-resident
// working set. Leave the loop exactly as proven.

template <int FOUT, bool RELU, bool OUT_BF16>
__global__ __launch_bounds__(512) void k_fused(
    const unsigned short* __restrict__ xin,  // [N,128] bf16
    const unsigned short* __restrict__ WtP,  // fragment-ordered weights
    const float* __restrict__ bias,          // [FOUT]
    const int* __restrict__ gcnt,            // [TNBKT] bin counts
    const unsigned* __restrict__ gbin,       // [TNBKT][TCAP] records
    unsigned short* __restrict__ outb,       // [N,FOUT] bf16 (if OUT_BF16)
    float* __restrict__ outf)                // [N,FOUT] fp32 (else)
{
    constexpr int NBt = FOUT / 16;           // 8 (L1) / 4 (L2)
    __shared__ __align__(16) unsigned short As0[16][136];      // 4.25 KB (root)
    __shared__ __align__(16) unsigned short As[8][16][136];    // 34 KB
    __shared__ unsigned short sorted[TCAP];                    // 1 KB src16 by key
    __shared__ int dcnt[128];                                  // per-key degree
    __shared__ int kbeg[128];                                  // per-key begin
    __shared__ int kcur[128];                                  // scatter cursors

    const int t = threadIdx.x;
    const int node0 = blockIdx.x * 16;

    // ---- P0: zero counters, stage seg0, read my bin record ----
    if (t < 128) { dcnt[t] = 0; kcur[t] = 0; }
    if (t < 128) {
        const int sr = t >> 3;
        const int sp = t & 7;
        const uint4* s4 = (const uint4*)(xin + (size_t)(node0 + sr) * 128 + sp * 16);
        uint4 r0 = s4[0], r1 = s4[1];
        uint4* d = (uint4*)&As0[sr][sp * 16];
        d[0] = r0; d[1] = r1;
    }
    const int nraw = gcnt[blockIdx.x];
    const int n = nraw < TCAP ? nraw : TCAP;
    unsigned rec = 0;
    if (t < n) rec = gbin[(size_t)blockIdx.x * TCAP + t];
    __syncthreads();   // bar1: zeros visible

    // ---- P1: per-key histogram ----
    if (t < n) atomicAdd(&dcnt[rec & 127], 1);
    __syncthreads();   // bar2

    // ---- P2: wave-0 exclusive scan over 128 keys ----
    if (t < 64) {
        int d0 = dcnt[2 * t], d1 = dcnt[2 * t + 1];
        int s = d0 + d1;
        int inc = s;
#pragma unroll
        for (int off = 1; off < 64; off <<= 1) {
            int y = __shfl_up(inc, off, 64);
            if (t >= off) inc += y;
        }
        int excl = inc - s;
        kbeg[2 * t]     = excl;
        kbeg[2 * t + 1] = excl + d0;
    }
    __syncthreads();   // bar3

    // ---- P3: scatter-sort records into per-key src lists ----
    if (t < n) {
        int key = rec & 127;
        int pos = atomicAdd(&kcur[key], 1);
        sorted[kbeg[key] + pos] = (unsigned short)(rec >> 7);
    }
    __syncthreads();   // bar4: sorted/dcnt/kbeg ready

    // ---- P4: gather, one chain per (node, rel), 4 lanes (32-feat quarters) ----
    {
        const int key = t >> 2;        // nl*8 + rel
        const int q   = t & 3;         // 32-feat quarter
        const int rel = key & 7;
        const int nl  = key >> 3;

        const int beg = kbeg[key];
        const int deg = dcnt[key];
        const int end = beg + deg;

        const unsigned short* bx = xin + q * 32;
        float a[32];
#pragma unroll
        for (int i = 0; i < 32; ++i) a[i] = 0.f;

        int j = beg;
        for (; j + 1 < end; j += 2) {
            int s0 = sorted[j];
            int s1 = sorted[j + 1];
            const uint4* p0 = (const uint4*)(bx + (size_t)s0 * 128);
            const uint4* p1 = (const uint4*)(bx + (size_t)s1 * 128);
            uint4 v0 = p0[0], v1 = p0[1], v2 = p0[2], v3 = p0[3];
            uint4 w0 = p1[0], w1 = p1[1], w2 = p1[2], w3 = p1[3];
            acc16(a, v0, v1);
            acc16(a + 16, v2, v3);
            acc16(a, w0, w1);
            acc16(a + 16, w2, w3);
        }
        if (j < end) {
            int s = sorted[j];
            const uint4* p = (const uint4*)(bx + (size_t)s * 128);
            uint4 v0 = p[0], v1 = p[1], v2 = p[2], v3 = p[3];
            acc16(a, v0, v1);
            acc16(a + 16, v2, v3);
        }

        float scl = 1.f / (float)(deg > 1 ? deg : 1);
        unsigned int pk[16];
#pragma unroll
        for (int i = 0; i < 16; ++i)
            pk[i] = (unsigned int)f2bf(a[i * 2] * scl) |
                    ((unsigned int)f2bf(a[i * 2 + 1] * scl) << 16);
        // swizzled stores: row-local granule (q*4+i) ^ rel
        uint4* G = (uint4*)&As[rel][nl][0];
        const int g0 = q * 4;
        G[(g0 + 0) ^ rel] = make_uint4(pk[0],  pk[1],  pk[2],  pk[3]);
        G[(g0 + 1) ^ rel] = make_uint4(pk[4],  pk[5],  pk[6],  pk[7]);
        G[(g0 + 2) ^ rel] = make_uint4(pk[8],  pk[9],  pk[10], pk[11]);
        G[(g0 + 3) ^ rel] = make_uint4(pk[12], pk[13], pk[14], pk[15]);
    }

    __syncthreads();   // bar5: all 9 A slabs ready

    // ---- P5: MFMA, wave w owns col-tile w ----
    const int lane = t & 63;
    const int w = t >> 6;
    if (w >= NBt) return;            // FOUT=64: waves 4-7 done (no barriers after)
    const int quad = lane >> 4;
    const int tc = lane & 15;

    f32x4 acc = (f32x4){0.f, 0.f, 0.f, 0.f};
    const bf16x8* Bp = (const bf16x8*)WtP;

#pragma unroll
    for (int seg = 0; seg < 9; ++seg) {
        const uint4* Ag = (seg == 0) ? (const uint4*)&As0[tc][0]
                                     : (const uint4*)&As[seg - 1][tc][0];
        const int s = (seg == 0) ? 0 : (seg - 1);   // un-swizzle (uniform per instr)
#pragma unroll
        for (int kk = 0; kk < 4; ++kk) {
            bf16x8 af = *(const bf16x8*)(Ag + (((kk << 2) + quad) ^ s));
            bf16x8 bf = Bp[((seg * 4 + kk) * NBt + w) * 64 + lane];
            acc = __builtin_amdgcn_mfma_f32_16x16x32_bf16(af, bf, acc, 0, 0, 0);
        }
    }

    // epilogue: D layout col = lane&15, row = quad*4 + reg
    const int col = w * 16 + tc;
    const float bs = bias[col];
#pragma unroll
    for (int i = 0; i < 4; ++i) {
        int r = node0 + quad * 4 + i;
        float v = acc[i] + bs;
        if (RELU) v = fmaxf(v, 0.f);
        if (OUT_BF16) outb[(size_t)r * FOUT + col] = f2bf(v);
        else          outf[(size_t)r * FOUT + col] = v;
    }
}

// ---------------- launch ----------------

extern "C" void kernel_launch(void* const* d_in, const int* in_sizes, int n_in,
                              void* d_out, int out_size, void* d_ws, size_t ws_size,
                              hipStream_t stream) {
    const float* x     = (const float*)d_in[0];
    const int*   ei    = (const int*)d_in[1];  // [2][E]: row0=src, row1=dst
    const int*   et    = (const int*)d_in[2];  // [E]
    const float* W1    = (const float*)d_in[3];
    const float* root1 = (const float*)d_in[4];
    const float* b1    = (const float*)d_in[5];
    const float* W2    = (const float*)d_in[6];
    const float* root2 = (const float*)d_in[7];
    const float* b2    = (const float*)d_in[8];
    float* out = (float*)d_out;

    int* ws = (int*)d_ws;
    int* gcur = ws;                                   // [3200] (TNBKT padded)
    unsigned* gbin = (unsigned*)(gcur + 3200);        // TNBKT*TCAP u32 = 6.4 MB
    unsigned short* xb  = (unsigned short*)(gbin + (size_t)TNBKT * TCAP); // 12.8 MB
    unsigned short* hb  = xb + (size_t)N_NODES * 128;                     // 12.8 MB
    unsigned short* Wt1 = hb + (size_t)N_NODES * 128;                     // 288 KB
    unsigned short* Wt2 = Wt1 + W1_ELEMS;                                 // 144 KB
    // total ws usage ~32.5 MB (ws = 256 MiB)

    const int* esrc = ei;
    const int* edst = ei + N_EDGES;

    // memset + 3 kernels: prep (bin ∥ convert) -> fused x2
    hipMemsetAsync(gcur, 0, 3200 * sizeof(int), stream);
    k_prep<<<NB_PREP, 256, 0, stream>>>(esrc, edst, et, gcur, gbin,
                                        x, xb, root1, W1, root2, W2, Wt1, Wt2);

    const int NT = N_NODES / 16;  // 3125 exactly

    k_fused<128, true,  true ><<<NT, 512, 0, stream>>>(xb, Wt1, b1, gcur, gbin, hb, nullptr);
    k_fused<64,  false, false><<<NT, 512, 0, stream>>>(hb, Wt2, b2, gcur, gbin, nullptr, out);
}

// Round 11
// 244.792 us; speedup vs baseline: 1.3548x; 1.0241x over previous
//
#include <hip/hip_runtime.h>

#define N_NODES 50000
#define N_EDGES 800000
#define R_REL   8

// two-level binning: coarse bucket (256 dst-nodes) -> tile (16 dst-nodes)
#define NCB     196                      // coarse buckets: dst>>8
#define CCAP    5120                     // records per coarse bucket (mean 4082, +16 sigma)
#define TNBKT   3125                     // tiles: 50000/16
#define TCAP    512                      // records per tile (mean 256, +16 sigma)
#define SLAB    4096                     // edges per bin-block
#define BINBLK  ((N_EDGES + SLAB - 1) / SLAB)  // 196

typedef float  f32x4  __attribute__((ext_vector_type(4)));
typedef __bf16 bf16x8 __attribute__((ext_vector_type(8)));

__device__ __forceinline__ unsigned short f2bf(float f) {
    unsigned int u = __float_as_uint(f);
    u = (u + 0x7FFFu + ((u >> 16) & 1u)) >> 16;   // RNE
    return (unsigned short)u;
}
__device__ __forceinline__ float bflo(unsigned int u) { return __uint_as_float(u << 16); }
__device__ __forceinline__ float bfhi(unsigned int u) { return __uint_as_float(u & 0xFFFF0000u); }

__device__ __forceinline__ void acc16(float* a, uint4 u0, uint4 u1) {
    a[0]  += bflo(u0.x);   a[1]  += bfhi(u0.x);
    a[2]  += bflo(u0.y);   a[3]  += bfhi(u0.y);
    a[4]  += bflo(u0.z);   a[5]  += bfhi(u0.z);
    a[6]  += bflo(u0.w);   a[7]  += bfhi(u0.w);
    a[8]  += bflo(u1.x);   a[9]  += bfhi(u1.x);
    a[10] += bflo(u1.y);   a[11] += bfhi(u1.y);
    a[12] += bflo(u1.z);   a[13] += bfhi(u1.z);
    a[14] += bflo(u1.w);   a[15] += bfhi(u1.w);
}

// ---------------- merged prep: COARSE binning + converts in ONE dispatch ----------------
// R7 diagnostic: per-(block,bin) runs of ~1.3 records across a multi-XCD-shared
// region give ~16x write-back amplification (WRITE_SIZE 52.9 MB for 3.2 MB of
// records) -- each 64B line is dirtied by ~12 blocks on different non-coherent
// XCD L2s. Fix: bin to 196 COARSE buckets (dst>>8): per-block runs ~21 records
// (84B) -> each line owned by ~1 block -> ~1.3x write-back. Histogram shrinks
// 3125->196 (1 sweep iteration, not 12). Record = src<<11 | ltile<<7 | localkey.

#define W1_ELEMS (9 * 128 * 128)   // NBt=8
#define W2_ELEMS (9 * 64 * 128)    // NBt=4
#define N4       (N_NODES * 32)    // 1.6M float4 groups
#define NB_CVT   ((N4 + 255) / 256)            // 6250
#define NB_PREP  (BINBLK + NB_CVT)             // 6446

__global__ __launch_bounds__(256) void k_prep(
    const int* __restrict__ src, const int* __restrict__ dst,
    const int* __restrict__ et, int* __restrict__ gcur1,
    unsigned* __restrict__ cbin,
    const float* __restrict__ x, unsigned short* __restrict__ xb,
    const float* __restrict__ root1, const float* __restrict__ W1,
    const float* __restrict__ root2, const float* __restrict__ W2,
    unsigned short* __restrict__ Wt1, unsigned short* __restrict__ Wt2)
{
    __shared__ int hist[256];
    __shared__ int base[256];
    const int t = threadIdx.x;

    if (blockIdx.x < BINBLK) {
        // ---------- coarse-bin branch ----------
        const int e0 = blockIdx.x * SLAB;
        hist[t] = 0;
        __syncthreads();
#pragma unroll
        for (int i = 0; i < SLAB / 256; ++i) {
            int e = e0 + i * 256 + t;
            if (e < N_EDGES) atomicAdd(&hist[dst[e] >> 8], 1);
        }
        __syncthreads();
        {
            int h = hist[t];
            base[t] = (h > 0) ? atomicAdd(&gcur1[t], h) : 0;
            hist[t] = 0;   // reuse as sub-cursor
        }
        __syncthreads();
#pragma unroll
        for (int i = 0; i < SLAB / 256; ++i) {
            int e = e0 + i * 256 + t;
            if (e < N_EDGES) {
                int d = dst[e];
                int b = d >> 8;
                int sub = atomicAdd(&hist[b], 1);
                int pos = base[b] + sub;
                // rec: src(16b) | ltile(4b) | localkey(7b)
                unsigned rec = ((unsigned)src[e] << 11) |
                               ((unsigned)((d >> 4) & 15) << 7) |
                               (unsigned)((d & 15) * 8 + et[e]);
                if (pos < CCAP) cbin[(size_t)b * CCAP + pos] = rec;
            }
        }
        return;
    }

    // ---------- convert branch ----------
    const int idx = (blockIdx.x - BINBLK) * 256 + t;
    if (idx < N4) {
        float4 v = *(const float4*)(x + (size_t)idx * 4);
        ushort4 o;
        o.x = f2bf(v.x); o.y = f2bf(v.y); o.z = f2bf(v.z); o.w = f2bf(v.w);
        *(ushort4*)(xb + (size_t)idx * 4) = o;
    }
    if (idx < W1_ELEMS) {
        int j    = idx & 7;
        int lane = (idx >> 3) & 63;
        int r    = idx >> 9;
        int nb   = r & 7;        // NBt = 8
        int r2   = r >> 3;
        int kk   = r2 & 3;
        int seg  = r2 >> 2;
        int k = kk * 32 + (lane >> 4) * 8 + j;
        int n = nb * 16 + (lane & 15);
        float v = (seg == 0) ? root1[k * 128 + n] : W1[((seg - 1) * 128 + k) * 128 + n];
        Wt1[idx] = f2bf(v);
    } else if (idx < W1_ELEMS + W2_ELEMS) {
        int i2   = idx - W1_ELEMS;
        int j    = i2 & 7;
        int lane = (i2 >> 3) & 63;
        int r    = i2 >> 9;
        int nb   = r & 3;        // NBt = 4
        int r2   = r >> 2;
        int kk   = r2 & 3;
        int seg  = r2 >> 2;
        int k = kk * 32 + (lane >> 4) * 8 + j;
        int n = nb * 16 + (lane & 15);
        float v = (seg == 0) ? root2[k * 64 + n] : W2[((seg - 1) * 128 + k) * 64 + n];
        Wt2[i2] = f2bf(v);
    }
}

// ---------------- part2: refine coarse buckets into per-tile gbin ----------------
// Block b owns coarse bucket b (16 exclusive tiles): coalesced read of its
// ~4083 records, LDS cursor per tile, write gbin[tile*TCAP + sub]. Every gbin
// line is written by exactly ONE block -> single-XCD ownership, no thrash.
// Emits the identical gbin/gcnt interface k_fused already consumes.

__global__ __launch_bounds__(256) void k_part2(
    const int* __restrict__ gcur1, const unsigned* __restrict__ cbin,
    unsigned* __restrict__ gbin, int* __restrict__ gcnt)
{
    __shared__ int cur[16];
    const int t = threadIdx.x;
    const int b = blockIdx.x;
    if (t < 16) cur[t] = 0;
    __syncthreads();
    const int nraw = gcur1[b];
    const int n = nraw < CCAP ? nraw : CCAP;
    const unsigned* rp = cbin + (size_t)b * CCAP;
    for (int j = t; j < n; j += 256) {
        unsigned rec = rp[j];
        int lt = (rec >> 7) & 15;
        int sub = atomicAdd(&cur[lt], 1);
        if (sub < TCAP) {
            unsigned outrec = ((rec >> 11) << 7) | (rec & 127);   // src<<7 | localkey
            gbin[(size_t)(b * 16 + lt) * TCAP + sub] = outrec;
        }
    }
    __syncthreads();
    if (t < 16) {
        int c = cur[t];
        gcnt[b * 16 + t] = c < TCAP ? c : TCAP;
    }
}

// ---------------- fused: in-LDS CSR build + gather + MFMA (R4/R5 proven) ----------------
// Gather-loop verdict after 10 rounds: at the per-CU outstanding-line
// latency-product wall. (R1 -29% halving lines-in-flight; R5 prefetch undone;
// R6 forced pipeline -8%; R9 phased quarter-gather -50%.) Left untouched.

template <int FOUT, bool RELU, bool OUT_BF16>
__global__ __launch_bounds__(512) void k_fused(
    const unsigned short* __restrict__ xin,  // [N,128] bf16
    const unsigned short* __restrict__ WtP,  // fragment-ordered weights
    const float* __restrict__ bias,          // [FOUT]
    const int* __restrict__ gcnt,            // [TNBKT] tile counts
    const unsigned* __restrict__ gbin,       // [TNBKT][TCAP] records
    unsigned short* __restrict__ outb,       // [N,FOUT] bf16 (if OUT_BF16)
    float* __restrict__ outf)                // [N,FOUT] fp32 (else)
{
    constexpr int NBt = FOUT / 16;           // 8 (L1) / 4 (L2)
    __shared__ __align__(16) unsigned short As0[16][136];      // 4.25 KB (root)
    __shared__ __align__(16) unsigned short As[8][16][136];    // 34 KB
    __shared__ unsigned short sorted[TCAP];                    // 1 KB src16 by key
    __shared__ int dcnt[128];                                  // per-key degree
    __shared__ int kbeg[128];                                  // per-key begin
    __shared__ int kcur[128];                                  // scatter cursors

    const int t = threadIdx.x;
    const int node0 = blockIdx.x * 16;

    // ---- P0: zero counters, stage seg0, read my bin record ----
    if (t < 128) { dcnt[t] = 0; kcur[t] = 0; }
    if (t < 128) {
        const int sr = t >> 3;
        const int sp = t & 7;
        const uint4* s4 = (const uint4*)(xin + (size_t)(node0 + sr) * 128 + sp * 16);
        uint4 r0 = s4[0], r1 = s4[1];
        uint4* d = (uint4*)&As0[sr][sp * 16];
        d[0] = r0; d[1] = r1;
    }
    const int nraw = gcnt[blockIdx.x];
    const int n = nraw < TCAP ? nraw : TCAP;
    unsigned rec = 0;
    if (t < n) rec = gbin[(size_t)blockIdx.x * TCAP + t];
    __syncthreads();   // bar1: zeros visible

    // ---- P1: per-key histogram ----
    if (t < n) atomicAdd(&dcnt[rec & 127], 1);
    __syncthreads();   // bar2

    // ---- P2: wave-0 exclusive scan over 128 keys ----
    if (t < 64) {
        int d0 = dcnt[2 * t], d1 = dcnt[2 * t + 1];
        int s = d0 + d1;
        int inc = s;
#pragma unroll
        for (int off = 1; off < 64; off <<= 1) {
            int y = __shfl_up(inc, off, 64);
            if (t >= off) inc += y;
        }
        int excl = inc - s;
        kbeg[2 * t]     = excl;
        kbeg[2 * t + 1] = excl + d0;
    }
    __syncthreads();   // bar3

    // ---- P3: scatter-sort records into per-key src lists ----
    if (t < n) {
        int key = rec & 127;
        int pos = atomicAdd(&kcur[key], 1);
        sorted[kbeg[key] + pos] = (unsigned short)(rec >> 7);
    }
    __syncthreads();   // bar4: sorted/dcnt/kbeg ready

    // ---- P4: gather, one chain per (node, rel), 4 lanes (32-feat quarters) ----
    {
        const int key = t >> 2;        // nl*8 + rel
        const int q   = t & 3;         // 32-feat quarter
        const int rel = key & 7;
        const int nl  = key >> 3;

        const int beg = kbeg[key];
        const int deg = dcnt[key];
        const int end = beg + deg;

        const unsigned short* bx = xin + q * 32;
        float a[32];
#pragma unroll
        for (int i = 0; i < 32; ++i) a[i] = 0.f;

        int j = beg;
        for (; j + 1 < end; j += 2) {
            int s0 = sorted[j];
            int s1 = sorted[j + 1];
            const uint4* p0 = (const uint4*)(bx + (size_t)s0 * 128);
            const uint4* p1 = (const uint4*)(bx + (size_t)s1 * 128);
            uint4 v0 = p0[0], v1 = p0[1], v2 = p0[2], v3 = p0[3];
            uint4 w0 = p1[0], w1 = p1[1], w2 = p1[2], w3 = p1[3];
            acc16(a, v0, v1);
            acc16(a + 16, v2, v3);
            acc16(a, w0, w1);
            acc16(a + 16, w2, w3);
        }
        if (j < end) {
            int s = sorted[j];
            const uint4* p = (const uint4*)(bx + (size_t)s * 128);
            uint4 v0 = p[0], v1 = p[1], v2 = p[2], v3 = p[3];
            acc16(a, v0, v1);
            acc16(a + 16, v2, v3);
        }

        float scl = 1.f / (float)(deg > 1 ? deg : 1);
        unsigned int pk[16];
#pragma unroll
        for (int i = 0; i < 16; ++i)
            pk[i] = (unsigned int)f2bf(a[i * 2] * scl) |
                    ((unsigned int)f2bf(a[i * 2 + 1] * scl) << 16);
        // swizzled stores: row-local granule (q*4+i) ^ rel
        uint4* G = (uint4*)&As[rel][nl][0];
        const int g0 = q * 4;
        G[(g0 + 0) ^ rel] = make_uint4(pk[0],  pk[1],  pk[2],  pk[3]);
        G[(g0 + 1) ^ rel] = make_uint4(pk[4],  pk[5],  pk[6],  pk[7]);
        G[(g0 + 2) ^ rel] = make_uint4(pk[8],  pk[9],  pk[10], pk[11]);
        G[(g0 + 3) ^ rel] = make_uint4(pk[12], pk[13], pk[14], pk[15]);
    }

    __syncthreads();   // bar5: all 9 A slabs ready

    // ---- P5: MFMA, wave w owns col-tile w ----
    const int lane = t & 63;
    const int w = t >> 6;
    if (w >= NBt) return;            // FOUT=64: waves 4-7 done (no barriers after)
    const int quad = lane >> 4;
    const int tc = lane & 15;

    f32x4 acc = (f32x4){0.f, 0.f, 0.f, 0.f};
    const bf16x8* Bp = (const bf16x8*)WtP;

#pragma unroll
    for (int seg = 0; seg < 9; ++seg) {
        const uint4* Ag = (seg == 0) ? (const uint4*)&As0[tc][0]
                                     : (const uint4*)&As[seg - 1][tc][0];
        const int s = (seg == 0) ? 0 : (seg - 1);   // un-swizzle (uniform per instr)
#pragma unroll
        for (int kk = 0; kk < 4; ++kk) {
            bf16x8 af = *(const bf16x8*)(Ag + (((kk << 2) + quad) ^ s));
            bf16x8 bf = Bp[((seg * 4 + kk) * NBt + w) * 64 + lane];
            acc = __builtin_amdgcn_mfma_f32_16x16x32_bf16(af, bf, acc, 0, 0, 0);
        }
    }

    // epilogue: D layout col = lane&15, row = quad*4 + reg
    const int col = w * 16 + tc;
    const float bs = bias[col];
#pragma unroll
    for (int i = 0; i < 4; ++i) {
        int r = node0 + quad * 4 + i;
        float v = acc[i] + bs;
        if (RELU) v = fmaxf(v, 0.f);
        if (OUT_BF16) outb[(size_t)r * FOUT + col] = f2bf(v);
        else          outf[(size_t)r * FOUT + col] = v;
    }
}

// ---------------- launch ----------------

extern "C" void kernel_launch(void* const* d_in, const int* in_sizes, int n_in,
                              void* d_out, int out_size, void* d_ws, size_t ws_size,
                              hipStream_t stream) {
    const float* x     = (const float*)d_in[0];
    const int*   ei    = (const int*)d_in[1];  // [2][E]: row0=src, row1=dst
    const int*   et    = (const int*)d_in[2];  // [E]
    const float* W1    = (const float*)d_in[3];
    const float* root1 = (const float*)d_in[4];
    const float* b1    = (const float*)d_in[5];
    const float* W2    = (const float*)d_in[6];
    const float* root2 = (const float*)d_in[7];
    const float* b2    = (const float*)d_in[8];
    float* out = (float*)d_out;

    int* ws = (int*)d_ws;
    int* gcur1 = ws;                                  // [256]   coarse cursors
    int* gcnt  = ws + 256;                            // [3200]  tile counts
    unsigned* cbin = (unsigned*)(ws + 3456);          // NCB*CCAP u32 = 4.0 MB
    unsigned* gbin = cbin + (size_t)NCB * CCAP;       // TNBKT*TCAP u32 = 6.4 MB
    unsigned short* xb  = (unsigned short*)(gbin + (size_t)TNBKT * TCAP); // 12.8 MB
    unsigned short* hb  = xb + (size_t)N_NODES * 128;                     // 12.8 MB
    unsigned short* Wt1 = hb + (size_t)N_NODES * 128;                     // 288 KB
    unsigned short* Wt2 = Wt1 + W1_ELEMS;                                 // 144 KB
    // total ws usage ~37 MB (ws = 256 MiB)

    const int* esrc = ei;
    const int* edst = ei + N_EDGES;

    // memset + 4 kernels: prep (coarse-bin ∥ convert) -> part2 -> fused x2
    hipMemsetAsync(gcur1, 0, 256 * sizeof(int), stream);
    k_prep<<<NB_PREP, 256, 0, stream>>>(esrc, edst, et, gcur1, cbin,
                                        x, xb, root1, W1, root2, W2, Wt1, Wt2);
    k_part2<<<NCB, 256, 0, stream>>>(gcur1, cbin, gbin, gcnt);

    const int NT = N_NODES / 16;  // 3125 exactly

    k_fused<128, true,  true ><<<NT, 512, 0, stream>>>(xb, Wt1, b1, gcnt, gbin, hb, nullptr);
    k_fused<64,  false, false><<<NT, 512, 0, stream>>>(hb, Wt2, b2, gcnt, gbin, nullptr, out);
}